// Round 1
// baseline (26.783 us; speedup 1.0000x reference)
//
#include <hip/hip_runtime.h>
#include <math.h>

#define NBINS 512
#define THREADS 256

__device__ __forceinline__ float fast_exp2(float x) {
    return __builtin_amdgcn_exp2f(x);
}

// K1: each block handles `npb` gaussians, produces a 512-bin partial histogram.
__global__ __launch_bounds__(THREADS) void gauss_hist_main(
    const float* __restrict__ means,
    const float* __restrict__ scan_point,
    const float* __restrict__ colours,
    const float* __restrict__ coefficients,
    const float* __restrict__ opacities,
    const float* __restrict__ pre_act,
    const int*   __restrict__ view_id_p,
    float* __restrict__ partial,   // [gridDim.x][NBINS]
    int n, int npb)
{
    // SoA params in LDS: (r0, A, B, nh) + intensity. npb <= 256.
    __shared__ float4 sp4[256];
    __shared__ float  sI[256];

    const int tid = threadIdx.x;
    const int gbase = blockIdx.x * npb;

    if (tid < npb) {
        const int i = gbase + tid;
        float inten = 0.f, r0 = 0.f, A = 0.f, B = 0.f, nh = 0.f;
        if (i < n) {
            const int vid = view_id_p[0];
            const float op  = opacities[i + vid];     // (N,1)[:, view_id]
            const float col = colours[i];
            const float sig_op = 1.0f / (1.0f + __expf(-op));
            inten = sig_op * col * col;

            const float cf = 1.0f / (1.0f + __expf(-coefficients[i]));

            const float dx = means[3*i]   - scan_point[0];
            const float dy = means[3*i+1] - scan_point[1];
            const float dz = means[3*i+2] - scan_point[2];
            r0 = sqrtf(fmaf(dx, dx, fmaf(dy, dy, dz*dz)));

            float sigma = __expf(pre_act[i]);          // mean over 1 column = itself
            sigma = fmaxf(sigma, 0.005f);              // clip(sigma, BIN_RES/2)
            const float inv_s = 1.0f / sigma;

            // pdf = g*(coeff*sqrt(0.5/pi)/sigma + (1-coeff)*d/sigma^2)
            // pr  = clamp(pdf * 0.005, 0, 1)
            A  = cf * 0.3989422804014327f * inv_s * 0.005f;
            B  = (1.0f - cf) * inv_s * inv_s * 0.005f;
            // exp(-0.5 d^2/s^2) = exp2(-0.5*log2e * d^2/s^2)
            nh = -0.7213475204444817f * inv_s * inv_s;
        }
        sp4[tid] = make_float4(r0, A, B, nh);
        sI[tid]  = inten;
    }
    __syncthreads();

    // thread t owns bins t and t+256; r_[b] = 0.005*(b+1)
    const float r_b0 = 0.005f * (float)(tid + 1);
    const float r_b1 = 0.005f * (float)(tid + 257);
    float acc0 = 0.f, acc1 = 0.f;

    #pragma unroll 4
    for (int g = 0; g < npb; ++g) {
        const float4 p   = sp4[g];    // broadcast (no bank conflict)
        const float inten = sI[g];
        const float d0 = r_b0 - p.x;
        const float d1 = r_b1 - p.x;
        const float g0 = fast_exp2(p.w * d0 * d0);
        const float g1 = fast_exp2(p.w * d1 * d1);
        float pr0 = g0 * fmaf(p.z, d0, p.y);
        float pr1 = g1 * fmaf(p.z, d1, p.y);
        pr0 = fminf(fmaxf(pr0, 0.0f), 1.0f);
        pr1 = fminf(fmaxf(pr1, 0.0f), 1.0f);
        acc0 = fmaf(inten, pr0, acc0);
        acc1 = fmaf(inten, pr1, acc1);
    }

    float* out = partial + (size_t)blockIdx.x * NBINS;
    out[tid]       = acc0;   // coalesced
    out[tid + 256] = acc1;
}

// K2: one block per bin; deterministic tree reduction over G partials + 1/r^2.
__global__ __launch_bounds__(256) void gauss_hist_reduce(
    const float* __restrict__ partial, float* __restrict__ out, int G)
{
    const int b = blockIdx.x;      // bin index
    const int k = threadIdx.x;
    float s = 0.f;
    for (int g = k; g < G; g += 256)
        s += partial[(size_t)g * NBINS + b];

    // wave64 shuffle reduce
    #pragma unroll
    for (int off = 32; off > 0; off >>= 1)
        s += __shfl_down(s, off, 64);

    __shared__ float wsum[4];
    const int wave = k >> 6;
    if ((k & 63) == 0) wsum[wave] = s;
    __syncthreads();
    if (k == 0) {
        const float t = wsum[0] + wsum[1] + wsum[2] + wsum[3];
        const float r = 0.005f * (float)(b + 1);
        out[b] = t / (r * r);
    }
}

extern "C" void kernel_launch(void* const* d_in, const int* in_sizes, int n_in,
                              void* d_out, int out_size, void* d_ws, size_t ws_size,
                              hipStream_t stream) {
    const float* means        = (const float*)d_in[0];
    const float* scan_point   = (const float*)d_in[1];
    const float* colours      = (const float*)d_in[2];
    const float* coefficients = (const float*)d_in[3];
    const float* opacities    = (const float*)d_in[4];
    const float* pre_act      = (const float*)d_in[5];
    const int*   view_id      = (const int*)d_in[6];

    const int n = in_sizes[2];   // colours has N elements

    // Choose grid so the partial buffer fits the workspace (needs G*512*4 bytes).
    int G = 1024;
    while ((size_t)G * NBINS * sizeof(float) > ws_size && G > 64) G >>= 1;
    int npb = (n + G - 1) / G;
    if (npb > 256) npb = 256;                 // LDS arrays sized 256
    G = (n + npb - 1) / npb;

    float* partial = (float*)d_ws;
    float* out = (float*)d_out;

    gauss_hist_main<<<G, THREADS, 0, stream>>>(
        means, scan_point, colours, coefficients, opacities, pre_act,
        view_id, partial, n, npb);

    gauss_hist_reduce<<<NBINS, 256, 0, stream>>>(partial, out, G);
}

// Round 2
// 21.466 us; speedup vs baseline: 1.2477x; 1.2477x over previous
//
#include <hip/hip_runtime.h>
#include <math.h>

#define NBINS 512
#define K1_THREADS 256

// K1: one thread per gaussian. Walk only the active bin range
// [blo, bhi] (pdf == 0 left of the zero crossing due to the clamp;
// < 6e-13 beyond 7.5 sigma) and scatter into a per-block LDS histogram
// with hardware ds_add_f32 atomics. Params stay in registers -> no LDS
// broadcast reads at all (that was the old bottleneck).
__global__ __launch_bounds__(K1_THREADS) void gauss_scatter(
    const float* __restrict__ means,
    const float* __restrict__ scan_point,
    const float* __restrict__ colours,
    const float* __restrict__ coefficients,
    const float* __restrict__ opacities,
    const float* __restrict__ pre_act,
    const int*   __restrict__ view_id_p,
    float* __restrict__ partial,   // [gridDim.x][NBINS]
    int n)
{
    __shared__ float hist[NBINS];
    const int tid = threadIdx.x;
    hist[tid]       = 0.0f;
    hist[tid + 256] = 0.0f;
    __syncthreads();

    const int i = blockIdx.x * K1_THREADS + tid;
    if (i < n) {
        const int vid = view_id_p[0];
        const float op  = opacities[i + vid];      // (N,1)[:, view_id]
        const float col = colours[i];
        const float inten = (1.0f / (1.0f + __expf(-op))) * col * col;
        const float cf    = 1.0f / (1.0f + __expf(-coefficients[i]));

        const float dx = means[3*i]   - scan_point[0];
        const float dy = means[3*i+1] - scan_point[1];
        const float dz = means[3*i+2] - scan_point[2];
        const float r0 = sqrtf(fmaf(dx, dx, fmaf(dy, dy, dz*dz)));

        const float sigma = fmaxf(__expf(pre_act[i]), 0.005f);

        // e = (r - r0) * q, with q chosen so g = exp2(-e^2)
        const float q  = 0.8493218002880191f / sigma;  // sqrt(0.5*log2(e))/sigma
        const float c  = inten * 0.005f;               // fold intensity + BIN_RES/2
        const float A2 = c * cf * 0.3989422804014327f / sigma;
        const float B3 = c * (1.0f - cf) / (0.8493218002880191f * sigma);

        // active range: pdf >= 0 for r >= r0 - (cf/(1-cf))*0.39894*sigma,
        // negligible for r > r0 + 7.5*sigma. r_[b] = 0.005*(b+1).
        const float rlo = r0 - (cf / (1.0f - cf)) * 0.3989422804014327f * sigma;
        const float rhi = r0 + 7.5f * sigma;
        int blo = (int)ceilf(rlo * 200.0f - 1.0f);
        int bhi = (int)floorf(rhi * 200.0f - 1.0f);
        blo = max(blo, 0);
        bhi = min(bhi, NBINS - 1);

        float e = (0.005f * (float)(blo + 1) - r0) * q;
        const float de = 0.005f * q;
        for (int b = blo; b <= bhi; ++b) {
            const float g = __builtin_amdgcn_exp2f(-(e * e));
            const float t = g * fmaf(B3, e, A2);   // inten*pr, upper clamp never binds
            unsafeAtomicAdd(&hist[b], t);          // ds_add_f32
            e += de;
        }
    }
    __syncthreads();

    float* out = partial + (size_t)blockIdx.x * NBINS;
    out[tid]       = hist[tid];        // coalesced
    out[tid + 256] = hist[tid + 256];
}

// K2: one block per bin; deterministic reduction over G partials + 1/r^2.
__global__ __launch_bounds__(256) void gauss_reduce(
    const float* __restrict__ partial, float* __restrict__ out, int G)
{
    const int b = blockIdx.x;
    const int k = threadIdx.x;
    float s = 0.0f;
    for (int g = k; g < G; g += 256)
        s += partial[(size_t)g * NBINS + b];

    #pragma unroll
    for (int off = 32; off > 0; off >>= 1)
        s += __shfl_down(s, off, 64);

    __shared__ float wsum[4];
    if ((k & 63) == 0) wsum[k >> 6] = s;
    __syncthreads();
    if (k == 0) {
        const float t = wsum[0] + wsum[1] + wsum[2] + wsum[3];
        const float r = 0.005f * (float)(b + 1);
        out[b] = t / (r * r);
    }
}

extern "C" void kernel_launch(void* const* d_in, const int* in_sizes, int n_in,
                              void* d_out, int out_size, void* d_ws, size_t ws_size,
                              hipStream_t stream) {
    const float* means        = (const float*)d_in[0];
    const float* scan_point   = (const float*)d_in[1];
    const float* colours      = (const float*)d_in[2];
    const float* coefficients = (const float*)d_in[3];
    const float* opacities    = (const float*)d_in[4];
    const float* pre_act      = (const float*)d_in[5];
    const int*   view_id      = (const int*)d_in[6];

    const int n = in_sizes[2];                  // colours has N elements
    const int G = (n + K1_THREADS - 1) / K1_THREADS;   // 512 for N=131072

    float* partial = (float*)d_ws;              // G*NBINS*4 bytes = 1 MB
    float* out = (float*)d_out;

    gauss_scatter<<<G, K1_THREADS, 0, stream>>>(
        means, scan_point, colours, coefficients, opacities, pre_act,
        view_id, partial, n);

    gauss_reduce<<<NBINS, 256, 0, stream>>>(partial, out, G);
}